// Round 1
// baseline (17208.543 us; speedup 1.0000x reference)
//
#include <hip/hip_runtime.h>
#include <math.h>

#define T_SEQ 2048
#define DD 1024
#define HH 4096
#define NLAYER 8
#define VV 50257
#define LN_EPS 1e-5f

// ---------------- LayerNorm (one block per row, D=1024, 256 thr x float4) ----
// If tok != nullptr, row is gathered from `in` at tok[blockIdx.x] (embedding).
__global__ __launch_bounds__(256) void ln_kernel(
    const float* __restrict__ in, const float* __restrict__ w,
    const float* __restrict__ b, float* __restrict__ out,
    const int* __restrict__ tok)
{
    int t = blockIdx.x;
    int tid = threadIdx.x;
    long rowi = tok ? (long)tok[t] : (long)t;
    const float4* rp = (const float4*)(in + rowi * DD);
    float4 xv = rp[tid];
    float s = xv.x + xv.y + xv.z + xv.w;
    float q = xv.x * xv.x + xv.y * xv.y + xv.z * xv.z + xv.w * xv.w;
    #pragma unroll
    for (int off = 32; off > 0; off >>= 1) {
        s += __shfl_down(s, off);
        q += __shfl_down(q, off);
    }
    __shared__ float ss[4], sq[4];
    __shared__ float mu_s, inv_s;
    int wave = tid >> 6, lane = tid & 63;
    if (lane == 0) { ss[wave] = s; sq[wave] = q; }
    __syncthreads();
    if (tid == 0) {
        float ts = ss[0] + ss[1] + ss[2] + ss[3];
        float tq = sq[0] + sq[1] + sq[2] + sq[3];
        float mu = ts * (1.0f / DD);
        float var = tq * (1.0f / DD) - mu * mu;   // population var (jnp.var)
        mu_s = mu;
        inv_s = rsqrtf(var + LN_EPS);
    }
    __syncthreads();
    float mu = mu_s, inv = inv_s;
    float4 wv = ((const float4*)w)[tid];
    float4 bv = ((const float4*)b)[tid];
    float4 o;
    o.x = (xv.x - mu) * inv * wv.x + bv.x;
    o.y = (xv.y - mu) * inv * wv.y + bv.y;
    o.z = (xv.z - mu) * inv * wv.z + bv.z;
    o.w = (xv.w - mu) * inv * wv.w + bv.w;
    ((float4*)(out + (size_t)t * DD))[tid] = o;
}

// ---------------- token-shift mix: o_j = x*m_j + shift(x)*(1-m_j) -----------
__global__ __launch_bounds__(256) void mix_kernel(
    const float* __restrict__ x,
    const float* __restrict__ m0, const float* __restrict__ m1,
    const float* __restrict__ m2,
    float* __restrict__ o0, float* __restrict__ o1, float* __restrict__ o2)
{
    int idx = blockIdx.x * 256 + threadIdx.x;
    int d = idx & (DD - 1);
    float xc = x[idx];
    float xp = (idx >= DD) ? x[idx - DD] : 0.0f;  // t=0 row gets zeros
    float m;
    m = m0[d]; o0[idx] = xc * m + xp * (1.0f - m);
    m = m1[d]; o1[idx] = xc * m + xp * (1.0f - m);
    if (m2) { m = m2[d]; o2[idx] = xc * m + xp * (1.0f - m); }
}

// ---------------- elementwise product ---------------------------------------
__global__ __launch_bounds__(256) void prod_kernel(
    const float* __restrict__ a, const float* __restrict__ b,
    float* __restrict__ o)
{
    int i = blockIdx.x * 256 + threadIdx.x;
    o[i] = a[i] * b[i];
}

// ---------------- WKV recurrence: one thread per channel --------------------
__global__ __launch_bounds__(256) void wkv_kernel(
    const float* __restrict__ k, const float* __restrict__ v,
    const float* __restrict__ td, const float* __restrict__ tf,
    float* __restrict__ y)
{
    int c = blockIdx.x * 256 + threadIdx.x;   // 1024 threads total
    float w = -expf(td[c]);
    float u = tf[c];
    float aa = 0.f, bb = 0.f, pp = -1e30f;
    for (int t = 0; t < T_SEQ; ++t) {
        int idx = t * DD + c;
        float kt = k[idx], vt = v[idx];
        float ww = u + kt;
        float qq = fmaxf(pp, ww);
        float e1 = expf(pp - qq), e2 = expf(ww - qq);
        y[idx] = (e1 * aa + e2 * vt) / (e1 * bb + e2);
        float ww2 = pp + w;
        float qq2 = fmaxf(ww2, kt);
        e1 = expf(ww2 - qq2); e2 = expf(kt - qq2);
        aa = e1 * aa + e2 * vt;
        bb = e1 * bb + e2;
        pp = qq2;
    }
}

// ---------------- fp32 tiled GEMM, C[M,N] (+epilogue) = A[M,K] @ B[K,N] -----
// mode 0: store   1: sigmoid   2: relu^2   3: C += AB   4: C += mul .* AB
#define BM 64
#define BN 64
#define BK 16

__global__ __launch_bounds__(256) void gemm_kernel(
    const float* __restrict__ A, const float* __restrict__ B,
    float* __restrict__ C, int M, int N, int K, int mode,
    const float* __restrict__ mul)
{
    __shared__ float As[BK][BM];   // transposed A tile (no pad: keep b128 reads)
    __shared__ float Bs[BK][BN];
    int tid = threadIdx.x;
    int tx = tid & 15, ty = tid >> 4;
    int bm = blockIdx.y * BM, bn = blockIdx.x * BN;
    int arow = tid >> 2;          // 0..63
    int acol = (tid & 3) << 2;    // 0,4,8,12
    int brow = tid >> 4;          // 0..15
    int bcol = (tid & 15) << 2;   // 0..60
    bool bvec = ((N & 3) == 0);   // head GEMM (N=50257) -> guarded scalar loads
    float acc[4][4] = {{0.f}};
    for (int k0 = 0; k0 < K; k0 += BK) {
        float4 a4 = *(const float4*)(A + (size_t)(bm + arow) * K + k0 + acol);
        As[acol + 0][arow] = a4.x;
        As[acol + 1][arow] = a4.y;
        As[acol + 2][arow] = a4.z;
        As[acol + 3][arow] = a4.w;
        const float* bp = B + (size_t)(k0 + brow) * N + bn + bcol;
        float4 b4;
        if (bvec) {
            b4 = *(const float4*)bp;
        } else {
            int nrem = N - (bn + bcol);
            b4.x = (nrem > 0) ? bp[0] : 0.0f;
            b4.y = (nrem > 1) ? bp[1] : 0.0f;
            b4.z = (nrem > 2) ? bp[2] : 0.0f;
            b4.w = (nrem > 3) ? bp[3] : 0.0f;
        }
        *(float4*)(&Bs[brow][bcol]) = b4;
        __syncthreads();
        #pragma unroll
        for (int kk = 0; kk < BK; ++kk) {
            float4 a = *(const float4*)(&As[kk][ty << 2]);
            float4 bb = *(const float4*)(&Bs[kk][tx << 2]);
            float av[4] = {a.x, a.y, a.z, a.w};
            float bw[4] = {bb.x, bb.y, bb.z, bb.w};
            #pragma unroll
            for (int i = 0; i < 4; ++i)
                #pragma unroll
                for (int j = 0; j < 4; ++j)
                    acc[i][j] = fmaf(av[i], bw[j], acc[i][j]);
        }
        __syncthreads();
    }
    #pragma unroll
    for (int i = 0; i < 4; ++i) {
        int m = bm + (ty << 2) + i;   // M always multiple of 64 here
        #pragma unroll
        for (int j = 0; j < 4; ++j) {
            int n = bn + (tx << 2) + j;
            if (n < N) {
                size_t idx = (size_t)m * N + n;
                float val = acc[i][j];
                if (mode == 1) val = 1.0f / (1.0f + expf(-val));
                else if (mode == 2) { val = fmaxf(val, 0.0f); val *= val; }
                else if (mode == 3) val += C[idx];
                else if (mode == 4) val = C[idx] + mul[idx] * val;
                C[idx] = val;
            }
        }
    }
}

static inline void launch_gemm(const float* A, const float* B, float* C,
                               int M, int N, int K, int mode, const float* mul,
                               hipStream_t stream)
{
    dim3 grid((N + BN - 1) / BN, M / BM);
    gemm_kernel<<<grid, 256, 0, stream>>>(A, B, C, M, N, K, mode, mul);
}

extern "C" void kernel_launch(void* const* d_in, const int* in_sizes, int n_in,
                              void* d_out, int out_size, void* d_ws, size_t ws_size,
                              hipStream_t stream)
{
    const int*   tokens    = (const int*)  d_in[0];
    const float* emb       = (const float*)d_in[1];
    const float* tm_decay  = (const float*)d_in[2];
    const float* tm_first  = (const float*)d_in[3];
    const float* tm_mix_k  = (const float*)d_in[4];
    const float* tm_mix_v  = (const float*)d_in[5];
    const float* tm_mix_r  = (const float*)d_in[6];
    const float* tm_Wk     = (const float*)d_in[7];
    const float* tm_Wv     = (const float*)d_in[8];
    const float* tm_Wr     = (const float*)d_in[9];
    const float* tm_Wo     = (const float*)d_in[10];
    const float* cm_mix_k  = (const float*)d_in[11];
    const float* cm_mix_r  = (const float*)d_in[12];
    const float* cm_Wk     = (const float*)d_in[13];
    const float* cm_Wv     = (const float*)d_in[14];
    const float* cm_Wr     = (const float*)d_in[15];
    const float* ln0_w     = (const float*)d_in[16];
    const float* ln0_b     = (const float*)d_in[17];
    const float* ln1_w     = (const float*)d_in[18];
    const float* ln1_b     = (const float*)d_in[19];
    const float* ln2_w     = (const float*)d_in[20];
    const float* ln2_b     = (const float*)d_in[21];
    const float* ln_out_w  = (const float*)d_in[22];
    const float* ln_out_b  = (const float*)d_in[23];
    const float* head_W    = (const float*)d_in[24];
    float* out = (float*)d_out;
    float* ws  = (float*)d_ws;

    const size_t TD = (size_t)T_SEQ * DD;
    // workspace layout: 8 x [T,D] buffers + 1 x [T,H] buffer = 96 MB
    if (ws_size < (8 * TD + (size_t)T_SEQ * HH) * sizeof(float)) return;
    float* x  = ws;            // residual stream
    float* xn = ws + 1 * TD;   // LN2 / LN_out output
    float* a0 = ws + 2 * TD;   // mix-k input, later y, later cm mix-k
    float* a1 = ws + 3 * TD;   // mix-v input, later r*y, later cm mix-r
    float* a2 = ws + 4 * TD;   // mix-r input
    float* bk = ws + 5 * TD;   // k
    float* bv = ws + 6 * TD;   // v
    float* br = ws + 7 * TD;   // r, later rr
    float* kk = ws + 8 * TD;   // [T,H]

    const int EW_GRID = (int)(TD / 256);   // 8192 blocks for [T,D] elementwise

    // x = LN0(emb[tokens])
    ln_kernel<<<T_SEQ, 256, 0, stream>>>(emb, ln0_w, ln0_b, x, tokens);

    for (int l = 0; l < NLAYER; ++l) {
        const size_t oD  = (size_t)l * DD;
        const size_t oDD = (size_t)l * DD * DD;
        const size_t oDH = (size_t)l * DD * HH;

        // x = LN1(x)  (faithful: LN1 output becomes the residual stream)
        ln_kernel<<<T_SEQ, 256, 0, stream>>>(x, ln1_w + oD, ln1_b + oD, x, nullptr);
        // token-shift mixes for k/v/r
        mix_kernel<<<EW_GRID, 256, 0, stream>>>(x, tm_mix_k + oD, tm_mix_v + oD,
                                                tm_mix_r + oD, a0, a1, a2);
        launch_gemm(a0, tm_Wk + oDD, bk, T_SEQ, DD, DD, 0, nullptr, stream);        // k
        launch_gemm(a1, tm_Wv + oDD, bv, T_SEQ, DD, DD, 0, nullptr, stream);        // v
        launch_gemm(a2, tm_Wr + oDD, br, T_SEQ, DD, DD, 1, nullptr, stream);        // r=sigmoid
        // y = wkv(-exp(td), tf, k, v)   -> a0
        wkv_kernel<<<DD / 256, 256, 0, stream>>>(bk, bv, tm_decay + oD, tm_first + oD, a0);
        // ry = r .* y -> a1
        prod_kernel<<<EW_GRID, 256, 0, stream>>>(br, a0, a1);
        // x += ry @ Wo
        launch_gemm(a1, tm_Wo + oDD, x, T_SEQ, DD, DD, 3, nullptr, stream);

        // xn = LN2(x)
        ln_kernel<<<T_SEQ, 256, 0, stream>>>(x, ln2_w + oD, ln2_b + oD, xn, nullptr);
        // channel-mix token-shift mixes
        mix_kernel<<<EW_GRID, 256, 0, stream>>>(xn, cm_mix_k + oD, cm_mix_r + oD,
                                                nullptr, a0, a1, nullptr);
        // kk = relu(a0 @ CWk)^2   [T,H]
        launch_gemm(a0, cm_Wk + oDH, kk, T_SEQ, HH, DD, 2, nullptr, stream);
        // rr = sigmoid(a1 @ CWr)  [T,D]
        launch_gemm(a1, cm_Wr + oDD, br, T_SEQ, DD, DD, 1, nullptr, stream);
        // x += rr .* (kk @ CWv)
        launch_gemm(kk, cm_Wv + (size_t)l * HH * DD, x, T_SEQ, DD, HH, 4, br, stream);
    }

    // out = LN_out(x) @ head_W
    ln_kernel<<<T_SEQ, 256, 0, stream>>>(x, ln_out_w, ln_out_b, xn, nullptr);
    launch_gemm(xn, head_W, out, T_SEQ, VV, DD, 0, nullptr, stream);
}